// Round 7
// baseline (144.175 us; speedup 1.0000x reference)
//
#include <hip/hip_runtime.h>
#include <hip/hip_bf16.h>
#include <stdint.h>

// out[i][j] = dot(x[i], y[j]) / max(|x[i]|*|y[j]|, 1e-8) / 0.05
// x,y: [4096,1024] f32; out: [4096,4096] f32
#define MDIM 4096
#define NDIM 4096
#define KDIM 1024
#define TEMP_INV 20.0f
#define BM 256
#define BN 128
#define BK 64

typedef __bf16 bf16x8 __attribute__((ext_vector_type(8)));
typedef float f32x16 __attribute__((ext_vector_type(16)));

typedef __attribute__((address_space(3))) void lds_void_t;
typedef __attribute__((address_space(1))) void glb_void_t;

__device__ __forceinline__ void async_copy16(const void* g, void* l) {
    __builtin_amdgcn_global_load_lds((glb_void_t*)(uintptr_t)g,
                                     (lds_void_t*)(uint32_t)(uintptr_t)l,
                                     16, 0, 0);
}

__device__ __forceinline__ unsigned short f32_to_bf16_rne(float f) {
    union { float f; uint32_t u; } v;
    v.f = f;
    uint32_t u = v.u;
    return (unsigned short)((u + 0x7FFFu + ((u >> 16) & 1u)) >> 16);
}

// ---------------------------------------------------------------------------
// Pack kernel: convert f32 rows -> bf16 in MFMA-FRAGMENT-PACKED order + norms.
// Packed layout (8-elem granules): granule((rb,ktG,s,l)) at linear index
//   ((rb*16 + ktG)*4 + s)*64 + l   holding src[rb*32 + (l&31)][ktG*64 + s*16 + (l>>5)*8 ..+8]
// so the GEMM's global_load_lds reads are fully contiguous 1 KB per wave-instr
// while depositing the (verified) R6 fragment-packed LDS image.
// One block per 32-row block (rb) per matrix; 4 panels of 256 cols via LDS.
#define PSTRIDE 260  // dwords: 1040 B = 16B-aligned, stride%32==4 -> <=4-way
__global__ __launch_bounds__(256) void pack_kernel(const float* __restrict__ x,
                                                   const float* __restrict__ y,
                                                   unsigned short* __restrict__ xp,
                                                   unsigned short* __restrict__ yp,
                                                   float* __restrict__ rnx,
                                                   float* __restrict__ rny) {
    __shared__ float lds[32 * PSTRIDE];  // 33.3 KB
    __shared__ float rsum[32];

    const int rb = blockIdx.x;
    const float* src = blockIdx.y ? y : x;
    unsigned short* dst = blockIdx.y ? yp : xp;
    float* rn = blockIdx.y ? rny : rnx;

    const int tid = threadIdx.x;
    const int lane = tid & 63;
    const int wv = tid >> 6;  // wave == s group in phase B

    if (tid < 32) rsum[tid] = 0.0f;
    __syncthreads();

    float accn = 0.0f;

    for (int p = 0; p < 4; ++p) {
        // Phase A: coalesced global read of 32x256 f32 panel -> LDS.
#pragma unroll
        for (int i = 0; i < 8; ++i) {
            const int f = i * 256 + tid;     // float4 index in panel
            const int row = f >> 6;          // 0..31
            const int c4 = f & 63;           // 0..63
            float4 v = *(const float4*)(src + (size_t)(rb * 32 + row) * KDIM + p * 256 + c4 * 4);
            *(float4*)(&lds[row * PSTRIDE + c4 * 4]) = v;
        }
        __syncthreads();

        // Phase B: read fragment granules, convert, coalesced packed store.
        // q = i*256+tid -> ktl = i, s = wv, l = lane (fixed row per thread).
#pragma unroll
        for (int i = 0; i < 4; ++i) {
            const int ktl = i;
            const int col = ktl * 64 + wv * 16 + (lane >> 5) * 8;
            const float* sp = &lds[(lane & 31) * PSTRIDE + col];
            float4 v0 = *(const float4*)(sp);
            float4 v1 = *(const float4*)(sp + 4);
            accn += v0.x * v0.x + v0.y * v0.y + v0.z * v0.z + v0.w * v0.w;
            accn += v1.x * v1.x + v1.y * v1.y + v1.z * v1.z + v1.w * v1.w;
            union { unsigned short u[8]; uint4 q4; } ob;
            ob.u[0] = f32_to_bf16_rne(v0.x); ob.u[1] = f32_to_bf16_rne(v0.y);
            ob.u[2] = f32_to_bf16_rne(v0.z); ob.u[3] = f32_to_bf16_rne(v0.w);
            ob.u[4] = f32_to_bf16_rne(v1.x); ob.u[5] = f32_to_bf16_rne(v1.y);
            ob.u[6] = f32_to_bf16_rne(v1.z); ob.u[7] = f32_to_bf16_rne(v1.w);
            const size_t go = ((size_t)(rb * 16 + p * 4 + ktl) * 4 + wv) * 512 + lane * 8;
            *(uint4*)(dst + go) = ob.q4;
        }
        __syncthreads();  // LDS reused next panel
    }

    // Norms: thread covers fixed row (lane&31); combine halves then waves.
    accn += __shfl_xor(accn, 32);
    if ((lane & 32) == 0) atomicAdd(&rsum[lane & 31], accn);
    __syncthreads();
    if (tid < 32) rn[rb * 32 + tid] = 1.0f / fmaxf(sqrtf(rsum[tid]), 1e-8f);
}

// ---------------------------------------------------------------------------
// 256x128 tile, BK=64, 4 waves in 2x2, wave tile 128x64 (4x2 of 32x32x16).
// Inputs are fragment-packed: each DMA call reads a CONTIGUOUS 4 KB (rb,kt)
// block (1 KB contiguous per wave-instr) into the R6-verified LDS image.
// Compute reads: base + lane*16 -> conflict-free, no per-read index math.
__global__ __launch_bounds__(256, 2) void gemm_cos_kernel(const unsigned short* __restrict__ Xp,
                                                          const unsigned short* __restrict__ Yp,
                                                          const float* __restrict__ rnx,
                                                          const float* __restrict__ rny,
                                                          float* __restrict__ out) {
    __shared__ __bf16 As[BM * BK];  // 32 KB = 32 groups x 512 elems
    __shared__ __bf16 Bs[BN * BK];  // 16 KB = 16 groups x 512 elems

    const int tid = threadIdx.x;  // 0..255
    // XCD-aware swizzle: id&7 ~ XCD; give each XCD 2 bm rows, sweep bn within.
    const int id = blockIdx.x;
    const int xcd = id & 7;
    const int t = id >> 3;             // 0..63
    const int bm = xcd * 2 + (t >> 5); // 0..15
    const int bn = t & 31;             // 0..31

    const int lane = tid & 63;
    const int wv = tid >> 6;

    // Packed bases: granule stride per (rb,kt) block = 2048 ushorts (4 KB).
    const unsigned short* gA = Xp + (size_t)(bm * 8) * 16 * 2048 + tid * 8;
    const unsigned short* gB = Yp + (size_t)(bn * 4) * 16 * 2048 + tid * 8;
    __bf16* lA = As + tid * 8;
    __bf16* lB = Bs + tid * 8;

    // Compute-side fragment bases: a(i,s) at pA + (i*4+s)*512, b(j,s) at pB + (j*4+s)*512.
    const __bf16* pA = As + (wv >> 1) * 16 * 512 + lane * 8;  // rb base = (wv>>1)*4
    const __bf16* pB = Bs + (wv & 1) * 8 * 512 + lane * 8;    // nb base = (wv&1)*2

    f32x16 acc[4][2] = {};

    for (int kt = 0; kt < 16; ++kt) {
        __syncthreads();  // readers done with LDS
#pragma unroll
        for (int c = 0; c < 8; ++c)
            async_copy16(gA + (size_t)(c * 16 + kt) * 2048, lA + c * 2048);
#pragma unroll
        for (int c = 0; c < 4; ++c)
            async_copy16(gB + (size_t)(c * 16 + kt) * 2048, lB + c * 2048);
        __syncthreads();  // DMA drained + visible

#pragma unroll
        for (int s = 0; s < 4; ++s) {
            bf16x8 b0 = *(const bf16x8*)(pB + s * 512);
            bf16x8 b1 = *(const bf16x8*)(pB + (4 + s) * 512);
#pragma unroll
            for (int i = 0; i < 4; ++i) {
                bf16x8 a = *(const bf16x8*)(pA + (i * 4 + s) * 512);
                acc[i][0] = __builtin_amdgcn_mfma_f32_32x32x16_bf16(a, b0, acc[i][0], 0, 0, 0);
                acc[i][1] = __builtin_amdgcn_mfma_f32_32x32x16_bf16(a, b1, acc[i][1], 0, 0, 0);
            }
        }
    }

    // C/D layout (m74/m101): col = lane&31, row = (reg&3) + 8*(reg>>2) + 4*(lane>>5).
    const int n32 = lane & 31;
    const int half = lane >> 5;
    const int grb = bm * BM + (wv >> 1) * 128 + 4 * half;
    const int gcb = bn * BN + (wv & 1) * 64 + n32;
    const float sy0 = rny[gcb] * TEMP_INV;
    const float sy1 = rny[gcb + 32] * TEMP_INV;

#pragma unroll
    for (int i = 0; i < 4; ++i) {
#pragma unroll
        for (int r = 0; r < 16; ++r) {
            const int ro = (r & 3) + 8 * (r >> 2);
            const int grow = grb + i * 32 + ro;
            const float rx = rnx[grow];
            out[(size_t)grow * NDIM + gcb] = acc[i][0][r] * rx * sy0;
            out[(size_t)grow * NDIM + gcb + 32] = acc[i][1][r] * rx * sy1;
        }
    }
}

extern "C" void kernel_launch(void* const* d_in, const int* in_sizes, int n_in,
                              void* d_out, int out_size, void* d_ws, size_t ws_size,
                              hipStream_t stream) {
    const float* x = (const float*)d_in[0];
    const float* y = (const float*)d_in[1];
    float* out = (float*)d_out;

    char* ws = (char*)d_ws;
    unsigned short* Xp = (unsigned short*)ws;                              // 8 MB packed
    unsigned short* Yp = (unsigned short*)(ws + (size_t)MDIM * KDIM * 2);  // 8 MB packed
    float* rnx = (float*)(ws + (size_t)(MDIM + NDIM) * KDIM * 2);
    float* rny = rnx + MDIM;

    pack_kernel<<<dim3(MDIM / 32, 2), 256, 0, stream>>>(x, y, Xp, Yp, rnx, rny);
    gemm_cos_kernel<<<dim3(512), 256, 0, stream>>>(Xp, Yp, rnx, rny, out);
}